// Round 3
// baseline (8779.986 us; speedup 1.0000x reference)
//
#include <hip/hip_runtime.h>
#include <hip/hip_bf16.h>

using bf16 = __hip_bfloat16;
typedef __attribute__((ext_vector_type(8))) short bf16x8;
typedef __attribute__((ext_vector_type(4))) float f32x4;

static constexpr int HD = 2048;   // hidden
static constexpr int BB = 512;    // batch
static constexpr int OD = 512;    // output dim
static constexpr int TT = 32;     // time steps

#define MFMA(a, b, c) __builtin_amdgcn_mfma_f32_16x16x32_bf16((a), (b), (c), 0, 0, 0)

__device__ __forceinline__ bf16x8 ldg8b(const bf16* p) { return *(const bf16x8*)p; }

// load 8 fp32, convert to bf16x8 (RNE via __float2bfloat16)
__device__ __forceinline__ bf16x8 cvt8(const float* p) {
  const float4 a = *(const float4*)p;
  const float4 b = *(const float4*)(p + 4);
  union { bf16x8 v; bf16 e[8]; } u;
  u.e[0] = __float2bfloat16(a.x); u.e[1] = __float2bfloat16(a.y);
  u.e[2] = __float2bfloat16(a.z); u.e[3] = __float2bfloat16(a.w);
  u.e[4] = __float2bfloat16(b.x); u.e[5] = __float2bfloat16(b.y);
  u.e[6] = __float2bfloat16(b.z); u.e[7] = __float2bfloat16(b.w);
  return u.v;
}

// one-time fp32 -> bf16 weight conversion (vectorized float4 -> 8B)
__global__ __launch_bounds__(256) void cvt_kernel(const float* __restrict__ s,
                                                  bf16* __restrict__ d, int n4) {
  const int i = blockIdx.x * 256 + threadIdx.x;
  if (i < n4) {
    const float4 v = ((const float4*)s)[i];
    union { unsigned long long u; bf16 e[4]; } o;
    o.e[0] = __float2bfloat16(v.x); o.e[1] = __float2bfloat16(v.y);
    o.e[2] = __float2bfloat16(v.z); o.e[3] = __float2bfloat16(v.w);
    *(unsigned long long*)(d + 4l * i) = o.u;
  }
}

// Fused GRU cell: block computes a 64x64 tile of h'. Gate GEMMs (r,z,n)
// accumulate over phase A (x @ Wih^T, K=Kx) then phase B (h @ Whh^T, K=HD);
// n keeps gx_n / gh_n separate for n = tanh(gx_n + r * gh_n).
// A operand staged fp32->bf16; W operand bf16 (pre-converted) or fp32 (wbf=0).
__global__ __launch_bounds__(256) void gru_cell_kernel(
    const float* __restrict__ Ax, int Kx,       // [B, Kx] fp32 layer input
    const float* __restrict__ Ah,               // [B, H] fp32 master h (also hprev)
    const void* __restrict__ Wih, const void* __restrict__ Whh, int wbf,
    const float* __restrict__ bih, const float* __restrict__ bhh,  // [3H] fp32
    float* __restrict__ hout) {                 // [B, H] fp32
  __shared__ __align__(16) bf16 smem[4 * 64 * 32];  // A, Wr, Wz, Wn tiles, 16 KB
  const int tid = threadIdx.x;
  const int lane = tid & 63;
  const int w = tid >> 6;
  const int srow = tid >> 2;                    // staging row 0..63
  const int sch = tid & 3;                      // 8-elem chunk 0..3
  const int m0 = blockIdx.y * 64;
  const int n0 = blockIdx.x * 64;
  const int wr = ((w >> 1) & 1) * 32;
  const int wc = (w & 1) * 32;
  const int kxs = Kx >> 5;
  const int nsteps = kxs + (HD >> 5);

  // acc: 0=r, 1=z (both phases), 2=gx_n (A), 3=gh_n (B)
  f32x4 acc[4][2][2];
#pragma unroll
  for (int a = 0; a < 4; ++a)
#pragma unroll
    for (int i = 0; i < 2; ++i)
#pragma unroll
      for (int j = 0; j < 2; ++j) acc[a][i][j] = (f32x4){0.f, 0.f, 0.f, 0.f};

  bf16x8 pf[4];
  auto wtile = [&](const void* W, long row, int K, int k) -> bf16x8 {
    if (wbf) return ldg8b((const bf16*)W + row * K + k);
    return cvt8((const float*)W + row * K + k);
  };
  auto loadr = [&](int s) {
    const bool pA = s < kxs;
    const float* A = pA ? Ax : Ah;
    const int K = pA ? Kx : HD;
    const int k = ((pA ? s : s - kxs) << 5) + sch * 8;
    const void* W = pA ? Wih : Whh;
    pf[0] = cvt8(A + (long)(m0 + srow) * K + k);
    pf[1] = wtile(W, n0 + srow, K, k);
    pf[2] = wtile(W, HD + n0 + srow, K, k);
    pf[3] = wtile(W, 2l * HD + n0 + srow, K, k);
  };
  auto store_lds = [&]() {
#pragma unroll
    for (int t = 0; t < 4; ++t)
      *(bf16x8*)(smem + t * 2048 + srow * 32 + sch * 8) = pf[t];
  };
  auto frg = [&](int t, int off) -> bf16x8 {
    return *(const bf16x8*)(smem + t * 2048 + (off + (lane & 15)) * 32 + (lane >> 4) * 8);
  };

  loadr(0);
  for (int s = 0; s < nsteps; ++s) {
    store_lds();
    __syncthreads();
    if (s + 1 < nsteps) loadr(s + 1);   // global prefetch overlaps MFMA
    bf16x8 af0 = frg(0, wr), af1 = frg(0, wr + 16);
    bf16x8 b00 = frg(1, wc), b01 = frg(1, wc + 16);
    bf16x8 b10 = frg(2, wc), b11 = frg(2, wc + 16);
    bf16x8 b20 = frg(3, wc), b21 = frg(3, wc + 16);
    acc[0][0][0] = MFMA(af0, b00, acc[0][0][0]);
    acc[0][1][0] = MFMA(af1, b00, acc[0][1][0]);
    acc[0][0][1] = MFMA(af0, b01, acc[0][0][1]);
    acc[0][1][1] = MFMA(af1, b01, acc[0][1][1]);
    acc[1][0][0] = MFMA(af0, b10, acc[1][0][0]);
    acc[1][1][0] = MFMA(af1, b10, acc[1][1][0]);
    acc[1][0][1] = MFMA(af0, b11, acc[1][0][1]);
    acc[1][1][1] = MFMA(af1, b11, acc[1][1][1]);
    if (s < kxs) {
      acc[2][0][0] = MFMA(af0, b20, acc[2][0][0]);
      acc[2][1][0] = MFMA(af1, b20, acc[2][1][0]);
      acc[2][0][1] = MFMA(af0, b21, acc[2][0][1]);
      acc[2][1][1] = MFMA(af1, b21, acc[2][1][1]);
    } else {
      acc[3][0][0] = MFMA(af0, b20, acc[3][0][0]);
      acc[3][1][0] = MFMA(af1, b20, acc[3][1][0]);
      acc[3][0][1] = MFMA(af0, b21, acc[3][0][1]);
      acc[3][1][1] = MFMA(af1, b21, acc[3][1][1]);
    }
    __syncthreads();
  }

  // C/D layout: col=lane&15, row=(lane>>4)*4+reg (m89-verified)
  const int q = lane >> 4, cl = lane & 15;
#pragma unroll
  for (int ni = 0; ni < 2; ++ni) {
    const int j = n0 + wc + ni * 16 + cl;
    const float bihr = bih[j], bihz = bih[j + HD], bihn = bih[j + 2 * HD];
    const float bhhr = bhh[j], bhhz = bhh[j + HD], bhhn = bhh[j + 2 * HD];
#pragma unroll
    for (int mi = 0; mi < 2; ++mi)
#pragma unroll
      for (int r = 0; r < 4; ++r) {
        const int b = m0 + wr + mi * 16 + q * 4 + r;
        const float gr = acc[0][mi][ni][r] + bihr + bhhr;
        const float gz = acc[1][mi][ni][r] + bihz + bhhz;
        const float gnx = acc[2][mi][ni][r] + bihn;
        const float gnh = acc[3][mi][ni][r] + bhhn;
        const float rr = 1.f / (1.f + __expf(-gr));
        const float zz = 1.f / (1.f + __expf(-gz));
        const float nn = tanhf(gnx + rr * gnh);
        const float hp = Ah[(long)b * HD + j];
        hout[(long)b * HD + j] = (1.f - zz) * nn + zz * hp;
      }
  }
}

// C = A @ W^T + bias (64x64 tiles). A fp32 (staged->bf16), W per wbf.
// mode 0: embedding — relu, scatter rows (b*2+l) into h0f/h1f
// mode 1: projection — write preds[b,t,:] (fp32) and xbuf (fp32)
__global__ __launch_bounds__(256) void gemm_bt_kernel(
    const float* __restrict__ A, const void* __restrict__ W, int wbf,
    const float* __restrict__ bias, int K, int mode, int t,
    float* __restrict__ o0, float* __restrict__ o1,
    float* __restrict__ preds, float* __restrict__ xbuf) {
  __shared__ __align__(16) bf16 smem[2 * 64 * 32];  // 8 KB
  const int tid = threadIdx.x;
  const int lane = tid & 63;
  const int w = tid >> 6;
  const int srow = tid >> 2;
  const int sch = tid & 3;
  const int m0 = blockIdx.y * 64;
  const int n0 = blockIdx.x * 64;
  const int wr = ((w >> 1) & 1) * 32;
  const int wc = (w & 1) * 32;
  const int nsteps = K >> 5;

  f32x4 acc[2][2];
#pragma unroll
  for (int i = 0; i < 2; ++i)
#pragma unroll
    for (int j = 0; j < 2; ++j) acc[i][j] = (f32x4){0.f, 0.f, 0.f, 0.f};

  bf16x8 pf[2];
  auto loadr = [&](int s) {
    const int k = (s << 5) + sch * 8;
    pf[0] = cvt8(A + (long)(m0 + srow) * K + k);
    if (wbf) pf[1] = ldg8b((const bf16*)W + (long)(n0 + srow) * K + k);
    else     pf[1] = cvt8((const float*)W + (long)(n0 + srow) * K + k);
  };
  auto store_lds = [&]() {
    *(bf16x8*)(smem + srow * 32 + sch * 8) = pf[0];
    *(bf16x8*)(smem + 2048 + srow * 32 + sch * 8) = pf[1];
  };
  auto frg = [&](int tile, int off) -> bf16x8 {
    return *(const bf16x8*)(smem + tile * 2048 + (off + (lane & 15)) * 32 + (lane >> 4) * 8);
  };

  loadr(0);
  for (int s = 0; s < nsteps; ++s) {
    store_lds();
    __syncthreads();
    if (s + 1 < nsteps) loadr(s + 1);
    bf16x8 a0 = frg(0, wr), a1 = frg(0, wr + 16);
    bf16x8 w0f = frg(1, wc), w1f = frg(1, wc + 16);
    acc[0][0] = MFMA(a0, w0f, acc[0][0]);
    acc[1][0] = MFMA(a1, w0f, acc[1][0]);
    acc[0][1] = MFMA(a0, w1f, acc[0][1]);
    acc[1][1] = MFMA(a1, w1f, acc[1][1]);
    __syncthreads();
  }

  const int q = lane >> 4, cl = lane & 15;
#pragma unroll
  for (int ni = 0; ni < 2; ++ni) {
    const int j = n0 + wc + ni * 16 + cl;
    const float bj = bias[j];
#pragma unroll
    for (int mi = 0; mi < 2; ++mi)
#pragma unroll
      for (int r = 0; r < 4; ++r) {
        const int row = m0 + wr + mi * 16 + q * 4 + r;
        float v = acc[mi][ni][r] + bj;
        if (mode == 0) {
          v = fmaxf(v, 0.f);
          const int b = row >> 1, l = row & 1;   // x rows are (b, l) pairs
          (l ? o1 : o0)[(long)b * HD + j] = v;
        } else {
          preds[((long)row * TT + t) * OD + j] = v;
          xbuf[(long)row * OD + j] = v;
        }
      }
  }
}

extern "C" void kernel_launch(void* const* d_in, const int* in_sizes, int n_in,
                              void* d_out, int out_size, void* d_ws, size_t ws_size,
                              hipStream_t stream) {
  // Reference dtypes are float32 throughout.
  const float* x    = (const float*)d_in[0];   // [512, 2, 1024]
  const float* embW = (const float*)d_in[1];   // [2048, 1024]
  const float* embb = (const float*)d_in[2];
  const float* Wih0 = (const float*)d_in[3];   // [6144, 512]
  const float* Whh0 = (const float*)d_in[4];   // [6144, 2048]
  const float* bih0 = (const float*)d_in[5];
  const float* bhh0 = (const float*)d_in[6];
  const float* Wih1 = (const float*)d_in[7];   // [6144, 2048]
  const float* Whh1 = (const float*)d_in[8];   // [6144, 2048]
  const float* bih1 = (const float*)d_in[9];
  const float* bhh1 = (const float*)d_in[10];
  const float* outW = (const float*)d_in[11];  // [512, 2048]
  const float* outb = (const float*)d_in[12];
  float* preds = (float*)d_out;                // [512, 32, 512] fp32

  char* p = (char*)d_ws;
  const size_t HF = (size_t)BB * HD * 4;       // 4 MB fp32 h-state
  float* h0f[2] = {(float*)p, (float*)(p + HF)}; p += 2 * HF;
  float* h1f[2] = {(float*)p, (float*)(p + HF)}; p += 2 * HF;
  float* xbuf = (float*)p; p += (size_t)BB * OD * 4;

  // optional pre-converted bf16 weights (saves 2x weight bytes per step)
  const int nE = 2048 * 1024, nI0 = 6144 * 512, nH = 6144 * 2048, nO = 512 * 2048;
  const size_t conv_bytes = 2ul * (nE + nI0 + 3ul * nH + nO) + 2ul * nH;  // slack
  const bool big = ws_size >= (size_t)(p - (char*)d_ws) + conv_bytes;
  bf16 *embWc = nullptr, *Wih0c = nullptr, *Whh0c = nullptr,
       *Wih1c = nullptr, *Whh1c = nullptr, *outWc = nullptr;
  if (big) {
    embWc = (bf16*)p; p += 2ul * nE;
    Wih0c = (bf16*)p; p += 2ul * nI0;
    Whh0c = (bf16*)p; p += 2ul * nH;
    Wih1c = (bf16*)p; p += 2ul * nH;
    Whh1c = (bf16*)p; p += 2ul * nH;
    outWc = (bf16*)p; p += 2ul * nO;
    auto cv = [&](const float* s, bf16* d, int n) {
      cvt_kernel<<<(n / 4 + 255) / 256, 256, 0, stream>>>(s, d, n / 4);
    };
    cv(embW, embWc, nE); cv(Wih0, Wih0c, nI0); cv(Whh0, Whh0c, nH);
    cv(Wih1, Wih1c, nH); cv(Whh1, Whh1c, nH); cv(outW, outWc, nO);
  }
  const int wbf = big ? 1 : 0;
  const void* embWs = big ? (const void*)embWc : (const void*)embW;
  const void* Wih0s = big ? (const void*)Wih0c : (const void*)Wih0;
  const void* Whh0s = big ? (const void*)Whh0c : (const void*)Whh0;
  const void* Wih1s = big ? (const void*)Wih1c : (const void*)Wih1;
  const void* Whh1s = big ? (const void*)Whh1c : (const void*)Whh1;
  const void* outWs = big ? (const void*)outWc : (const void*)outW;

  hipMemsetAsync(xbuf, 0, (size_t)BB * OD * 4, stream);  // first 2 steps: zero input

  // embedding: x as [1024, 1024] (rows b*2+l) -> h0f[0], h1f[0]
  gemm_bt_kernel<<<dim3(HD / 64, 1024 / 64), 256, 0, stream>>>(
      x, embWs, wbf, embb, 1024, 0, 0, h0f[0], h1f[0], nullptr, nullptr);

  for (int s = 0; s < 33; ++s) {
    const int cur = s & 1, nxt = cur ^ 1;
    gru_cell_kernel<<<dim3(HD / 64, BB / 64), 256, 0, stream>>>(
        xbuf, OD, h0f[cur], Wih0s, Whh0s, wbf, bih0, bhh0, h0f[nxt]);
    gru_cell_kernel<<<dim3(HD / 64, BB / 64), 256, 0, stream>>>(
        h0f[nxt], HD, h1f[cur], Wih1s, Whh1s, wbf, bih1, bhh1, h1f[nxt]);
    if (s >= 1)
      gemm_bt_kernel<<<dim3(OD / 64, BB / 64), 256, 0, stream>>>(
          h1f[nxt], outWs, wbf, outb, HD, 1, s - 1,
          nullptr, nullptr, preds, xbuf);
  }
}

// Round 4
// 5583.166 us; speedup vs baseline: 1.5726x; 1.5726x over previous
//
#include <hip/hip_runtime.h>
#include <hip/hip_bf16.h>

using bf16 = __hip_bfloat16;
typedef __attribute__((ext_vector_type(8))) short bf16x8;
typedef __attribute__((ext_vector_type(4))) float f32x4;

static constexpr int HD = 2048;   // hidden
static constexpr int BB = 512;    // batch
static constexpr int OD = 512;    // output dim
static constexpr int TT = 32;     // time steps
static constexpr int PS = 40;     // LDS row stride in elems (80 B, bank-conflict pad)

#define MFMA(a, b, c) __builtin_amdgcn_mfma_f32_16x16x32_bf16((a), (b), (c), 0, 0, 0)

__device__ __forceinline__ bf16x8 ldg8b(const bf16* p) { return *(const bf16x8*)p; }

__device__ __forceinline__ bf16x8 cvt8(const float* p) {
  const float4 a = *(const float4*)p;
  const float4 b = *(const float4*)(p + 4);
  union { bf16x8 v; bf16 e[8]; } u;
  u.e[0] = __float2bfloat16(a.x); u.e[1] = __float2bfloat16(a.y);
  u.e[2] = __float2bfloat16(a.z); u.e[3] = __float2bfloat16(a.w);
  u.e[4] = __float2bfloat16(b.x); u.e[5] = __float2bfloat16(b.y);
  u.e[6] = __float2bfloat16(b.z); u.e[7] = __float2bfloat16(b.w);
  return u.v;
}

// one-time fp32 -> bf16 weight conversion
__global__ __launch_bounds__(256) void cvt_kernel(const float* __restrict__ s,
                                                  bf16* __restrict__ d, int n4) {
  const int i = blockIdx.x * 256 + threadIdx.x;
  if (i < n4) {
    const float4 v = ((const float4*)s)[i];
    union { unsigned long long u; bf16 e[4]; } o;
    o.e[0] = __float2bfloat16(v.x); o.e[1] = __float2bfloat16(v.y);
    o.e[2] = __float2bfloat16(v.z); o.e[3] = __float2bfloat16(v.w);
    *(unsigned long long*)(d + 4l * i) = o.u;
  }
}

// Fused GRU cell, tile 32m x 64n, 4 waves (each 32m x 16n subtile, full K).
// Grid 512 blocks (2/CU). XCD swizzle: 16 m-tiles of one n-tile share an XCD.
__global__ __launch_bounds__(256) void gru_cell_kernel(
    const bf16* __restrict__ Ax, int Kx,        // [B, Kx] bf16 layer input
    const bf16* __restrict__ Ahb,               // [B, H] bf16 h shadow
    const float* __restrict__ hprevf,           // [B, H] fp32 h master
    const void* __restrict__ Wih, const void* __restrict__ Whh, int wbf,
    const float* __restrict__ bih, const float* __restrict__ bhh,
    float* __restrict__ houtf, bf16* __restrict__ houtb) {
  __shared__ __align__(16) bf16 smem[(32 + 3 * 64) * PS];  // A + Wr,Wz,Wn tiles
  bf16* const sA = smem;
  bf16* const sW0 = smem + 32 * PS;
  bf16* const sW1 = sW0 + 64 * PS;
  bf16* const sW2 = sW1 + 64 * PS;
  const int tid = threadIdx.x;
  const int lane = tid & 63;
  const int wv = tid >> 6;
  const int wc = wv * 16;                       // wave n-offset in 64-tile
  const int bid = blockIdx.x;
  const int m0 = ((bid >> 3) & 15) * 32;        // 16 m-tiles
  const int n0 = ((bid & 7) + 8 * (bid >> 7)) * 64;  // XCD-grouped n-tile
  const int kxs = Kx >> 5;
  const int nsteps = kxs + (HD >> 5);
  const int srow = tid >> 2, sch = tid & 3;     // W staging: 64 rows x 4 chunks

  // acc: 0=r, 1=z (both phases), 2=gx_n (A), 3=gh_n (B); [gate][mi]
  f32x4 acc[4][2];
#pragma unroll
  for (int a = 0; a < 4; ++a)
#pragma unroll
    for (int i = 0; i < 2; ++i) acc[a][i] = (f32x4){0.f, 0.f, 0.f, 0.f};

  bf16x8 pfA, pfW0, pfW1, pfW2;
  auto loadr = [&](int s) {
    const bool pA = s < kxs;
    const int K = pA ? Kx : HD;
    const int k = ((pA ? s : s - kxs) << 5) + sch * 8;
    if (tid < 128) {                            // A: 32 rows x 4 chunks
      const bf16* A = pA ? Ax : Ahb;
      pfA = ldg8b(A + (long)(m0 + (tid >> 2)) * K + k);
    }
    const void* W = pA ? Wih : Whh;
    const long r = n0 + srow;
    if (wbf) {
      pfW0 = ldg8b((const bf16*)W + r * K + k);
      pfW1 = ldg8b((const bf16*)W + (HD + r) * K + k);
      pfW2 = ldg8b((const bf16*)W + (2l * HD + r) * K + k);
    } else {
      pfW0 = cvt8((const float*)W + r * K + k);
      pfW1 = cvt8((const float*)W + (HD + r) * K + k);
      pfW2 = cvt8((const float*)W + (2l * HD + r) * K + k);
    }
  };
  auto store_lds = [&]() {
    if (tid < 128) *(bf16x8*)(sA + (tid >> 2) * PS + (tid & 3) * 8) = pfA;
    *(bf16x8*)(sW0 + srow * PS + sch * 8) = pfW0;
    *(bf16x8*)(sW1 + srow * PS + sch * 8) = pfW1;
    *(bf16x8*)(sW2 + srow * PS + sch * 8) = pfW2;
  };
  auto frg = [&](const bf16* t, int off) -> bf16x8 {
    return *(const bf16x8*)(t + (off + (lane & 15)) * PS + (lane >> 4) * 8);
  };

  loadr(0);
  for (int s = 0; s < nsteps; ++s) {
    store_lds();
    __syncthreads();
    if (s + 1 < nsteps) loadr(s + 1);           // prefetch overlaps MFMA
    bf16x8 af0 = frg(sA, 0), af1 = frg(sA, 16);
    bf16x8 b0 = frg(sW0, wc), b1 = frg(sW1, wc), b2 = frg(sW2, wc);
    acc[0][0] = MFMA(af0, b0, acc[0][0]);
    acc[0][1] = MFMA(af1, b0, acc[0][1]);
    acc[1][0] = MFMA(af0, b1, acc[1][0]);
    acc[1][1] = MFMA(af1, b1, acc[1][1]);
    if (s < kxs) {
      acc[2][0] = MFMA(af0, b2, acc[2][0]);
      acc[2][1] = MFMA(af1, b2, acc[2][1]);
    } else {
      acc[3][0] = MFMA(af0, b2, acc[3][0]);
      acc[3][1] = MFMA(af1, b2, acc[3][1]);
    }
    __syncthreads();
  }

  // C/D layout: col=lane&15, row=(lane>>4)*4+reg (m89-verified)
  const int q = lane >> 4, cl = lane & 15;
  const int j = n0 + wc + cl;
  const float bihr = bih[j], bihz = bih[j + HD], bihn = bih[j + 2 * HD];
  const float bhhr = bhh[j], bhhz = bhh[j + HD], bhhn = bhh[j + 2 * HD];
#pragma unroll
  for (int mi = 0; mi < 2; ++mi)
#pragma unroll
    for (int r = 0; r < 4; ++r) {
      const int b = m0 + mi * 16 + q * 4 + r;
      const float gr = acc[0][mi][r] + bihr + bhhr;
      const float gz = acc[1][mi][r] + bihz + bhhz;
      const float gnx = acc[2][mi][r] + bihn;
      const float gnh = acc[3][mi][r] + bhhn;
      const float rr = 1.f / (1.f + __expf(-gr));
      const float zz = 1.f / (1.f + __expf(-gz));
      const float nn = tanhf(gnx + rr * gnh);
      const float hp = hprevf[(long)b * HD + j];
      const float hn = (1.f - zz) * nn + zz * hp;
      houtf[(long)b * HD + j] = hn;
      houtb[(long)b * HD + j] = __float2bfloat16(hn);
    }
}

// C = A @ W^T + bias, tile 32m x 64n, 4 waves. Same staging/swizzle scheme.
// mode 0: embedding — relu, scatter rows (b*2+l) into h0/h1 (fp32+bf16)
// mode 1: projection — preds[b,t,:] fp32 + xbuf bf16
__global__ __launch_bounds__(256) void gemm32_kernel(
    const void* __restrict__ A, int abf, const void* __restrict__ W, int wbf,
    const float* __restrict__ bias, int K, int mode, int t, int mshift,
    float* __restrict__ o0f, bf16* __restrict__ o0b,
    float* __restrict__ o1f, bf16* __restrict__ o1b,
    float* __restrict__ preds, bf16* __restrict__ xbuf) {
  __shared__ __align__(16) bf16 smem[(32 + 64) * PS];
  bf16* const sA = smem;
  bf16* const sW = smem + 32 * PS;
  const int tid = threadIdx.x;
  const int lane = tid & 63;
  const int wv = tid >> 6;
  const int wc = wv * 16;
  const int bid = blockIdx.x;
  const int i = bid >> 3;
  const int m0 = (i & ((1 << mshift) - 1)) * 32;
  const int n0 = ((bid & 7) + 8 * (i >> mshift)) * 64;
  const int nsteps = K >> 5;
  const int srow = tid >> 2, sch = tid & 3;

  f32x4 acc[2];
  acc[0] = (f32x4){0.f, 0.f, 0.f, 0.f};
  acc[1] = (f32x4){0.f, 0.f, 0.f, 0.f};

  bf16x8 pfA, pfW;
  auto loadr = [&](int s) {
    const int k = (s << 5) + sch * 8;
    if (tid < 128) {
      const long off = (long)(m0 + (tid >> 2)) * K + k;
      pfA = abf ? ldg8b((const bf16*)A + off) : cvt8((const float*)A + off);
    }
    const long off = (long)(n0 + srow) * K + k;
    pfW = wbf ? ldg8b((const bf16*)W + off) : cvt8((const float*)W + off);
  };
  auto store_lds = [&]() {
    if (tid < 128) *(bf16x8*)(sA + (tid >> 2) * PS + (tid & 3) * 8) = pfA;
    *(bf16x8*)(sW + srow * PS + sch * 8) = pfW;
  };
  auto frg = [&](const bf16* tl, int off) -> bf16x8 {
    return *(const bf16x8*)(tl + (off + (lane & 15)) * PS + (lane >> 4) * 8);
  };

  loadr(0);
  for (int s = 0; s < nsteps; ++s) {
    store_lds();
    __syncthreads();
    if (s + 1 < nsteps) loadr(s + 1);
    bf16x8 af0 = frg(sA, 0), af1 = frg(sA, 16);
    bf16x8 bw = frg(sW, wc);
    acc[0] = MFMA(af0, bw, acc[0]);
    acc[1] = MFMA(af1, bw, acc[1]);
    __syncthreads();
  }

  const int q = lane >> 4, cl = lane & 15;
  const int j = n0 + wc + cl;
  const float bj = bias[j];
#pragma unroll
  for (int mi = 0; mi < 2; ++mi)
#pragma unroll
    for (int r = 0; r < 4; ++r) {
      const int row = m0 + mi * 16 + q * 4 + r;
      float v = acc[mi][r] + bj;
      if (mode == 0) {
        v = fmaxf(v, 0.f);
        const int b = row >> 1, l = row & 1;    // x rows are (b, l) pairs
        if (l == 0) { o0f[(long)b * HD + j] = v; o0b[(long)b * HD + j] = __float2bfloat16(v); }
        else        { o1f[(long)b * HD + j] = v; o1b[(long)b * HD + j] = __float2bfloat16(v); }
      } else {
        preds[((long)row * TT + t) * OD + j] = v;
        xbuf[(long)row * OD + j] = __float2bfloat16(v);
      }
    }
}

extern "C" void kernel_launch(void* const* d_in, const int* in_sizes, int n_in,
                              void* d_out, int out_size, void* d_ws, size_t ws_size,
                              hipStream_t stream) {
  const float* x    = (const float*)d_in[0];
  const float* embW = (const float*)d_in[1];
  const float* embb = (const float*)d_in[2];
  const float* Wih0 = (const float*)d_in[3];
  const float* Whh0 = (const float*)d_in[4];
  const float* bih0 = (const float*)d_in[5];
  const float* bhh0 = (const float*)d_in[6];
  const float* Wih1 = (const float*)d_in[7];
  const float* Whh1 = (const float*)d_in[8];
  const float* bih1 = (const float*)d_in[9];
  const float* bhh1 = (const float*)d_in[10];
  const float* outW = (const float*)d_in[11];
  const float* outb = (const float*)d_in[12];
  float* preds = (float*)d_out;

  char* p = (char*)d_ws;
  const size_t HF = (size_t)BB * HD * 4;
  const size_t HB = (size_t)BB * HD * 2;
  float* h0f[2] = {(float*)p, (float*)(p + HF)}; p += 2 * HF;
  float* h1f[2] = {(float*)p, (float*)(p + HF)}; p += 2 * HF;
  bf16* h0b[2] = {(bf16*)p, (bf16*)(p + HB)}; p += 2 * HB;
  bf16* h1b[2] = {(bf16*)p, (bf16*)(p + HB)}; p += 2 * HB;
  bf16* xbuf = (bf16*)p; p += (size_t)BB * OD * 2;

  const int nE = 2048 * 1024, nI0 = 6144 * 512, nH = 6144 * 2048, nO = 512 * 2048;
  const size_t conv_bytes = 2ul * (nE + nI0 + 3ul * nH + nO);
  const bool big = ws_size >= (size_t)(p - (char*)d_ws) + conv_bytes;
  bf16 *embWc = nullptr, *Wih0c = nullptr, *Whh0c = nullptr,
       *Wih1c = nullptr, *Whh1c = nullptr, *outWc = nullptr;
  if (big) {
    embWc = (bf16*)p; p += 2ul * nE;
    Wih0c = (bf16*)p; p += 2ul * nI0;
    Whh0c = (bf16*)p; p += 2ul * nH;
    Wih1c = (bf16*)p; p += 2ul * nH;
    Whh1c = (bf16*)p; p += 2ul * nH;
    outWc = (bf16*)p; p += 2ul * nO;
    auto cv = [&](const float* s, bf16* d, int n) {
      cvt_kernel<<<(n / 4 + 255) / 256, 256, 0, stream>>>(s, d, n / 4);
    };
    cv(embW, embWc, nE); cv(Wih0, Wih0c, nI0); cv(Whh0, Whh0c, nH);
    cv(Wih1, Wih1c, nH); cv(Whh1, Whh1c, nH); cv(outW, outWc, nO);
  }
  const int wbf = big ? 1 : 0;
  const void* embWs = big ? (const void*)embWc : (const void*)embW;
  const void* Wih0s = big ? (const void*)Wih0c : (const void*)Wih0;
  const void* Whh0s = big ? (const void*)Whh0c : (const void*)Whh0;
  const void* Wih1s = big ? (const void*)Wih1c : (const void*)Wih1;
  const void* Whh1s = big ? (const void*)Whh1c : (const void*)Whh1;
  const void* outWs = big ? (const void*)outWc : (const void*)outW;

  hipMemsetAsync(xbuf, 0, (size_t)BB * OD * 2, stream);  // zero input, steps 0-1

  // embedding: x as [1024,1024] (rows b*2+l), 32 m-tiles x 32 n-tiles
  gemm32_kernel<<<1024, 256, 0, stream>>>(
      x, 0, embWs, wbf, embb, 1024, 0, 0, 5,
      h0f[0], h0b[0], h1f[0], h1b[0], nullptr, nullptr);

  for (int s = 0; s < 33; ++s) {
    const int cur = s & 1, nxt = cur ^ 1;
    gru_cell_kernel<<<512, 256, 0, stream>>>(
        xbuf, OD, h0b[cur], h0f[cur], Wih0s, Whh0s, wbf, bih0, bhh0,
        h0f[nxt], h0b[nxt]);
    gru_cell_kernel<<<512, 256, 0, stream>>>(
        h0b[nxt], HD, h1b[cur], h1f[cur], Wih1s, Whh1s, wbf, bih1, bhh1,
        h1f[nxt], h1b[nxt]);
    if (s >= 1)
      gemm32_kernel<<<128, 256, 0, stream>>>(
          h1b[nxt], 1, outWs, wbf, outb, HD, 1, s - 1, 4,
          nullptr, nullptr, nullptr, nullptr, preds, xbuf);
  }
}